// Round 8
// baseline (320.587 us; speedup 1.0000x reference)
//
#include <hip/hip_runtime.h>
#include <hip/hip_bf16.h>
#include <cstdint>

#define NN 50000
#define NE 800000
#define DIM 256
#define NH 8
#define NB 196          // (NN+255)/256

typedef short v8s __attribute__((ext_vector_type(8)));
typedef float v4f __attribute__((ext_vector_type(4)));
typedef unsigned short u16x8 __attribute__((ext_vector_type(8)));

__device__ __forceinline__ float b2f(unsigned short u) {
    union { float f; uint32_t i; } c; c.i = ((uint32_t)u) << 16; return c.f;
}
__device__ __forceinline__ unsigned short f2b(float f) {
    union { float f; uint32_t i; } c; c.f = f;
    uint32_t lsb = (c.i >> 16) & 1u;
    return (unsigned short)((c.i + 0x7FFFu + lsb) >> 16);
}

// -------------------------------------------- prep: Wt (transposed bf16 W) +
// att-projection columns M2/M3: M2[k][h] = sum_c W[k][h*32+c]*ASRC[h][c].
// Wt layout: 272 rows x 256 k. Rows 0-255 = W^T; 256+h = M2 col h; 264+h = M3.
__global__ __launch_bounds__(256) void prep_kernel(
    const float* __restrict__ W, const float* __restrict__ ASRC,
    const float* __restrict__ ADST, unsigned short* __restrict__ Wt) {
    const int t = threadIdx.x;
    if (blockIdx.x < 256) {
        int idx = blockIdx.x * 256 + t;
        int k = idx >> 8, n = idx & 255;
        Wt[n * DIM + k] = f2b(W[k * DIM + n]);
    } else {
        // block 256: thread k computes the 16 att-projection entries for row k
        const int k = t;
        #pragma unroll
        for (int h = 0; h < NH; ++h) {
            float ss = 0.f, dd = 0.f;
            #pragma unroll
            for (int c4 = 0; c4 < 8; ++c4) {
                float4 wv = *(const float4*)(W + (size_t)k * DIM + h * 32 + c4 * 4);
                float4 av = *(const float4*)(ASRC + h * 32 + c4 * 4);
                float4 dv = *(const float4*)(ADST + h * 32 + c4 * 4);
                ss += wv.x * av.x + wv.y * av.y + wv.z * av.z + wv.w * av.w;
                dd += wv.x * dv.x + wv.y * dv.y + wv.z * dv.z + wv.w * dv.w;
            }
            Wt[(256 + h) * DIM + k] = f2b(ss);
            Wt[(264 + h) * DIM + k] = f2b(dd);
        }
    }
}

// ------------------------------- GEMM h = x@W (+ att logits, + deg histogram)
// BM=64 x BN=272 (256 H cols + 16 logit cols), 256 threads = 4 waves; each
// wave owns a 64-col strip, wave 0 additionally owns cols 256-271. BK=64.
// Degree histogram for the CSR build is folded into the prologue.
#define LDA3 72
__global__ __launch_bounds__(256) void gemm_kernel(
    const float* __restrict__ X, const unsigned short* __restrict__ Wt,
    const int* __restrict__ e, int* __restrict__ deg,
    unsigned short* __restrict__ H, float* __restrict__ a_srcW,
    float* __restrict__ a_dstW) {
    __shared__ __align__(16) unsigned short As[64 * LDA3];
    __shared__ __align__(16) unsigned short Bs[272 * LDA3];
    const int t = threadIdx.x;
    const int wc = t >> 6, lane = t & 63;
    const int fr = lane & 15, fq = lane >> 4;
    const int m0 = blockIdx.x * 64;

    // ---- degree histogram slice (overlaps with staging/compute) ----
    {
        int probe = e[2 * lane + 1];
        unsigned long long nz = __ballot(probe != 0);
        bool is64 = (nz == 0ull);
        int tg = blockIdx.x * 256 + t;
        #pragma unroll
        for (int j = 0; j < 4; ++j) {
            int i = tg * 4 + j;
            if (i < NE) {
                int d = is64 ? e[2 * (NE + i)] : e[NE + i];
                atomicAdd(&deg[d], 1);
            }
        }
    }

    v4f acc[4][4];
    v4f acc4[4];
    #pragma unroll
    for (int mi = 0; mi < 4; ++mi) {
        acc4[mi] = (v4f){0.f, 0.f, 0.f, 0.f};
        #pragma unroll
        for (int j = 0; j < 4; ++j) acc[mi][j] = (v4f){0.f, 0.f, 0.f, 0.f};
    }

    #pragma unroll
    for (int kt = 0; kt < 256; kt += 64) {
        // stage A: 64 rows x 64 f32 -> bf16 (1024 float4, 4/thread)
        #pragma unroll
        for (int it = 0; it < 4; ++it) {
            int v = t + it * 256;
            int row = v >> 4;
            int c4 = (v & 15) << 2;
            int gr = m0 + row;
            float4 val = make_float4(0.f, 0.f, 0.f, 0.f);
            if (gr < NN) val = *(const float4*)(X + (size_t)gr * DIM + kt + c4);
            ushort4 o;
            o.x = f2b(val.x); o.y = f2b(val.y); o.z = f2b(val.z); o.w = f2b(val.w);
            *(ushort4*)(As + row * LDA3 + c4) = o;
        }
        // stage B: 272 rows x 64 shorts (2176 vec8, ~8.5/thread)
        #pragma unroll
        for (int it = 0; it < 9; ++it) {
            int v = t + it * 256;
            if (v < 2176) {
                int row = v >> 3;
                int kv = (v & 7) << 3;
                u16x8 val = *(const u16x8*)(Wt + (size_t)row * DIM + kt + kv);
                *(u16x8*)(Bs + row * LDA3 + kv) = val;
            }
        }
        __syncthreads();
        #pragma unroll
        for (int ks = 0; ks < 64; ks += 32) {
            v8s a[4];
            #pragma unroll
            for (int mi = 0; mi < 4; ++mi)
                a[mi] = *(const v8s*)(As + (mi * 16 + fr) * LDA3 + ks + fq * 8);
            #pragma unroll
            for (int j = 0; j < 4; ++j) {
                v8s b = *(const v8s*)(Bs + (wc * 64 + j * 16 + fr) * LDA3 + ks + fq * 8);
                #pragma unroll
                for (int mi = 0; mi < 4; ++mi)
                    acc[mi][j] = __builtin_amdgcn_mfma_f32_16x16x32_bf16(a[mi], b, acc[mi][j], 0, 0, 0);
            }
            if (wc == 0) {   // att-logit columns 256-271 (wave-uniform branch)
                v8s b4 = *(const v8s*)(Bs + (256 + fr) * LDA3 + ks + fq * 8);
                #pragma unroll
                for (int mi = 0; mi < 4; ++mi)
                    acc4[mi] = __builtin_amdgcn_mfma_f32_16x16x32_bf16(a[mi], b4, acc4[mi], 0, 0, 0);
            }
        }
        __syncthreads();
    }
    // H write
    #pragma unroll
    for (int mi = 0; mi < 4; ++mi)
        #pragma unroll
        for (int j = 0; j < 4; ++j)
            #pragma unroll
            for (int r = 0; r < 4; ++r) {
                int gr = m0 + mi * 16 + fq * 4 + r;
                int gc = wc * 64 + j * 16 + fr;
                if (gr < NN) H[(size_t)gr * DIM + gc] = f2b(acc[mi][j][r]);
            }
    // att-logit write (wave 0): col 256+fr -> a_src head fr / a_dst head fr-8
    if (wc == 0) {
        #pragma unroll
        for (int mi = 0; mi < 4; ++mi)
            #pragma unroll
            for (int r = 0; r < 4; ++r) {
                int gr = m0 + mi * 16 + fq * 4 + r;
                if (gr < NN) {
                    if (fr < 8) a_srcW[gr * NH + fr] = acc4[mi][r];
                    else        a_dstW[gr * NH + (fr - 8)] = acc4[mi][r];
                }
            }
    }
}

// ------------------------------------------------------------- two-level scan
__global__ __launch_bounds__(256) void scan1_kernel(const int* __restrict__ deg,
                                                    int* __restrict__ row_start,
                                                    int* __restrict__ bsum) {
    const int t = threadIdx.x, b = blockIdx.x;
    const int i = b * 256 + t;
    const int lane = t & 63, wave = t >> 6;
    int v = (i < NN) ? deg[i] : 0;
    int x = v;
    #pragma unroll
    for (int off = 1; off <= 32; off <<= 1) {
        int y = __shfl_up(x, off);
        if (lane >= off) x += y;
    }
    __shared__ int wt[4];
    if (lane == 63) wt[wave] = x;
    __syncthreads();
    int add = 0;
    #pragma unroll
    for (int w2 = 0; w2 < 4; ++w2) if (w2 < wave) add += wt[w2];
    int incl = x + add;
    if (i < NN) row_start[i] = incl - v;
    if (t == 255) bsum[b] = incl;
}

__global__ __launch_bounds__(256) void scan2_kernel(const int* __restrict__ bsum,
                                                    int* __restrict__ boff,
                                                    int* __restrict__ row_start) {
    const int t = threadIdx.x;
    const int lane = t & 63, wave = t >> 6;
    int v = (t < NB) ? bsum[t] : 0;
    int x = v;
    #pragma unroll
    for (int off = 1; off <= 32; off <<= 1) {
        int y = __shfl_up(x, off);
        if (lane >= off) x += y;
    }
    __shared__ int wt[4];
    if (lane == 63) wt[wave] = x;
    __syncthreads();
    int add = 0;
    #pragma unroll
    for (int w2 = 0; w2 < 4; ++w2) if (w2 < wave) add += wt[w2];
    int incl = x + add;
    if (t < NB) boff[t] = incl - v;
    if (t == 255) row_start[NN] = incl;
}

__global__ __launch_bounds__(256) void scan3_kernel(int* __restrict__ row_start,
                                                    const int* __restrict__ boff,
                                                    int* __restrict__ cursor) {
    const int i = blockIdx.x * 256 + threadIdx.x;
    if (i < NN) {
        int r = row_start[i] + boff[blockIdx.x];
        row_start[i] = r;
        cursor[i] = r;
    }
}

// -------------------------------------- CSR fill + per-edge softmax weights
// weights stored bf16 (16B/edge) — halves scattered write + agg read bytes.
__global__ __launch_bounds__(256) void fill_kernel(
    const int* __restrict__ e, const float* __restrict__ a_src,
    const float* __restrict__ a_dst, int* __restrict__ cursor,
    int* __restrict__ csr_src, unsigned short* __restrict__ wcsr16) {
    const int i = blockIdx.x * 256 + threadIdx.x;
    const int lane = threadIdx.x & 63;
    int probe = e[2 * lane + 1];
    unsigned long long nz = __ballot(probe != 0);
    bool is64 = (nz == 0ull);
    int s, d;
    if (is64) { s = e[2 * i]; d = e[2 * (NE + i)]; }
    else      { s = e[i];     d = e[NE + i]; }
    int pos = atomicAdd(&cursor[d], 1);
    csr_src[pos] = s;
    float4 as0 = *(const float4*)(a_src + (size_t)s * NH);
    float4 as1 = *(const float4*)(a_src + (size_t)s * NH + 4);
    float4 ad0 = *(const float4*)(a_dst + (size_t)d * NH);
    float4 ad1 = *(const float4*)(a_dst + (size_t)d * NH + 4);
    const float* asp0 = (const float*)&as0; const float* asp1 = (const float*)&as1;
    const float* adp0 = (const float*)&ad0; const float* adp1 = (const float*)&ad1;
    u16x8 wv;
    #pragma unroll
    for (int h = 0; h < 4; ++h) {
        float lg = asp0[h] + adp0[h];
        lg = lg > 0.f ? lg : 0.2f * lg;
        wv[h] = f2b(__expf(lg));
        float lg2 = asp1[h] + adp1[h];
        lg2 = lg2 > 0.f ? lg2 : 0.2f * lg2;
        wv[4 + h] = f2b(__expf(lg2));
    }
    *(u16x8*)(wcsr16 + (size_t)pos * NH) = wv;
}

// --------------------------------------- fused aggregate+ELU+LayerNorm
// one wave per dst node; 16-edge chunks, slot=lane>>5 takes 8 contiguous
// edges -> 8 independent csr/w loads then 8 independent H-row loads in
// flight. q=lane&31 owns channels q*8..q*8+7.
__global__ __launch_bounds__(256) void agg_kernel(
    const unsigned short* __restrict__ H, const int* __restrict__ row_start,
    const int* __restrict__ csr_src, const unsigned short* __restrict__ wcsr16,
    const float* __restrict__ X, const float* __restrict__ BIAS,
    const float* __restrict__ LNS, const float* __restrict__ LNB,
    float* __restrict__ OUT) {
    const int wave = threadIdx.x >> 6, lane = threadIdx.x & 63;
    const int d = blockIdx.x * 4 + wave;
    if (d >= NN) return;
    const int base = row_start[d];
    const int degree = row_start[d + 1] - base;
    const int slot = lane >> 5;
    const int q = lane & 31;
    const int headq = q >> 2;

    float4 x0 = *(const float4*)(X + (size_t)d * DIM + q * 8);
    float4 x1 = *(const float4*)(X + (size_t)d * DIM + q * 8 + 4);
    float4 b0 = *(const float4*)(BIAS + q * 8);
    float4 b1 = *(const float4*)(BIAS + q * 8 + 4);
    float4 sc0 = *(const float4*)(LNS + q * 8);
    float4 sc1 = *(const float4*)(LNS + q * 8 + 4);
    float4 lb0 = *(const float4*)(LNB + q * 8);
    float4 lb1 = *(const float4*)(LNB + q * 8 + 4);

    float acc[8];
    #pragma unroll
    for (int j = 0; j < 8; ++j) acc[j] = 0.f;
    float sumw = 0.f;

    for (int c0 = 0; c0 < degree; c0 += 16) {
        const int e0 = c0 + slot * 8;
        const int rem = degree - e0;
        const size_t eb = (size_t)base + e0;
        int s[8]; float w[8];
        #pragma unroll
        for (int k = 0; k < 8; ++k) { s[k] = 0; w[k] = 0.f; }
        #pragma unroll
        for (int k = 0; k < 8; ++k)
            if (rem > k) {
                s[k] = csr_src[eb + k];
                w[k] = b2f(wcsr16[(eb + k) * NH + headq]);
            }
        u16x8 hv[8];
        #pragma unroll
        for (int k = 0; k < 8; ++k)
            hv[k] = *(const u16x8*)(H + (size_t)s[k] * DIM + q * 8);
        #pragma unroll
        for (int k = 0; k < 8; ++k) {
            sumw += w[k];
            #pragma unroll
            for (int j = 0; j < 8; ++j) acc[j] += w[k] * b2f(hv[k][j]);
        }
    }

    float sum_ex = sumw + __shfl_xor(sumw, 32);
    #pragma unroll
    for (int j = 0; j < 8; ++j) acc[j] += __shfl_xor(acc[j], 32);

    const float inv = 1.0f / (sum_ex + 1e-16f);

    const float* xp0 = (const float*)&x0; const float* xp1 = (const float*)&x1;
    const float* bp0 = (const float*)&b0; const float* bp1 = (const float*)&b1;
    float v[8];
    float s1v = 0.f, s2v = 0.f;
    #pragma unroll
    for (int j = 0; j < 8; ++j) {
        float xv = (j < 4) ? xp0[j] : xp1[j - 4];
        float bv = (j < 4) ? bp0[j] : bp1[j - 4];
        float t = acc[j] * inv + bv + xv;
        t = t > 0.f ? t : expm1f(t);   // ELU
        v[j] = t;
        s1v += t;
        s2v += t * t;
    }
    #pragma unroll
    for (int off = 16; off >= 1; off >>= 1) {
        s1v += __shfl_xor(s1v, off);
        s2v += __shfl_xor(s2v, off);
    }
    const float mean = s1v * (1.0f / 256.0f);
    float var = s2v * (1.0f / 256.0f) - mean * mean;
    var = fmaxf(var, 0.f);
    const float rstd = rsqrtf(var + 1e-5f);

    if (slot == 0) {
        const float* scp0 = (const float*)&sc0; const float* scp1 = (const float*)&sc1;
        const float* lbp0 = (const float*)&lb0; const float* lbp1 = (const float*)&lb1;
        float4 o0, o1;
        float* op0 = (float*)&o0; float* op1 = (float*)&o1;
        #pragma unroll
        for (int j = 0; j < 4; ++j) {
            op0[j] = (v[j] - mean) * rstd * scp0[j] + lbp0[j];
            op1[j] = (v[j + 4] - mean) * rstd * scp1[j] + lbp1[j];
        }
        *(float4*)(OUT + (size_t)d * DIM + q * 8) = o0;
        *(float4*)(OUT + (size_t)d * DIM + q * 8 + 4) = o1;
    }
}

// ---------------------------------------------------------------- launcher
extern "C" void kernel_launch(void* const* d_in, const int* in_sizes, int n_in,
                              void* d_out, int out_size, void* d_ws, size_t ws_size,
                              hipStream_t stream) {
    const float* X    = (const float*)d_in[0];
    const int*   EIDX = (const int*)d_in[1];
    const float* W    = (const float*)d_in[2];
    const float* ASRC = (const float*)d_in[3];
    const float* ADST = (const float*)d_in[4];
    const float* BIAS = (const float*)d_in[5];
    const float* LNS  = (const float*)d_in[6];
    const float* LNB  = (const float*)d_in[7];
    float* OUT = (float*)d_out;

    char* ws = (char*)d_ws;
    unsigned short* H   = (unsigned short*)(ws);                  // 25,600,000
    unsigned short* Wt  = (unsigned short*)(ws + 25600000);       //    139,264
    float* a_srcW       = (float*)(ws + 25739264);                //  1,600,000
    float* a_dstW       = (float*)(ws + 27339264);                //  1,600,000
    int*   deg          = (int*)(ws + 28939264);                  //    200,000
    int*   row_start    = (int*)(ws + 29139264);                  //    200,016
    int*   cursor       = (int*)(ws + 29339280);                  //    200,000
    int*   csr_src      = (int*)(ws + 29539280);                  //  3,200,000
    unsigned short* wcsr16 = (unsigned short*)(ws + 32739280);    // 12,800,000
    int*   bsum         = (int*)(ws + 45539280);                  //        784
    int*   boff         = (int*)(ws + 45540064);                  //        784

    hipMemsetAsync(deg, 0, NN * sizeof(int), stream);

    dim3 blk(256);
    prep_kernel<<<dim3(257), blk, 0, stream>>>(W, ASRC, ADST, Wt);
    gemm_kernel<<<dim3(782), blk, 0, stream>>>(X, Wt, EIDX, deg, H, a_srcW, a_dstW);
    scan1_kernel<<<dim3(NB), blk, 0, stream>>>(deg, row_start, bsum);
    scan2_kernel<<<dim3(1), blk, 0, stream>>>(bsum, boff, row_start);
    scan3_kernel<<<dim3(NB), blk, 0, stream>>>(row_start, boff, cursor);
    fill_kernel<<<dim3(NE / 256), blk, 0, stream>>>(EIDX, a_srcW, a_dstW, cursor, csr_src, wcsr16);
    agg_kernel<<<dim3((NN + 3) / 4), blk, 0, stream>>>(
        H, row_start, csr_src, wcsr16, X, BIAS, LNS, LNB, OUT);
}

// Round 9
// 314.736 us; speedup vs baseline: 1.0186x; 1.0186x over previous
//
#include <hip/hip_runtime.h>
#include <hip/hip_bf16.h>
#include <cstdint>

#define NN 50000
#define NE 800000
#define DIM 256
#define NH 8
#define NB 196          // (NN+255)/256

typedef short v8s __attribute__((ext_vector_type(8)));
typedef float v4f __attribute__((ext_vector_type(4)));
typedef unsigned short u16x8 __attribute__((ext_vector_type(8)));

__device__ __forceinline__ float b2f(unsigned short u) {
    union { float f; uint32_t i; } c; c.i = ((uint32_t)u) << 16; return c.f;
}
__device__ __forceinline__ unsigned short f2b(float f) {
    union { float f; uint32_t i; } c; c.f = f;
    uint32_t lsb = (c.i >> 16) & 1u;
    return (unsigned short)((c.i + 0x7FFFu + lsb) >> 16);
}

// -------------------------------------------- prep: Wt (transposed bf16 W) +
// att-projection columns: row 256+h = W[:,h-block]·att_src[h], 264+h = ·att_dst.
__global__ __launch_bounds__(256) void prep_kernel(
    const float* __restrict__ W, const float* __restrict__ ASRC,
    const float* __restrict__ ADST, unsigned short* __restrict__ Wt) {
    const int t = threadIdx.x;
    if (blockIdx.x < 256) {
        int idx = blockIdx.x * 256 + t;
        int k = idx >> 8, n = idx & 255;
        Wt[n * DIM + k] = f2b(W[k * DIM + n]);
    } else {
        const int k = t;
        #pragma unroll
        for (int h = 0; h < NH; ++h) {
            float ss = 0.f, dd = 0.f;
            #pragma unroll
            for (int c4 = 0; c4 < 8; ++c4) {
                float4 wv = *(const float4*)(W + (size_t)k * DIM + h * 32 + c4 * 4);
                float4 av = *(const float4*)(ASRC + h * 32 + c4 * 4);
                float4 dv = *(const float4*)(ADST + h * 32 + c4 * 4);
                ss += wv.x * av.x + wv.y * av.y + wv.z * av.z + wv.w * av.w;
                dd += wv.x * dv.x + wv.y * dv.y + wv.z * dv.z + wv.w * dv.w;
            }
            Wt[(256 + h) * DIM + k] = f2b(ss);
            Wt[(264 + h) * DIM + k] = f2b(dd);
        }
    }
}

// ------------------------------- GEMM h = x@W (+ att logits, + deg histogram)
#define LDA3 72
__global__ __launch_bounds__(256) void gemm_kernel(
    const float* __restrict__ X, const unsigned short* __restrict__ Wt,
    const int* __restrict__ e, int* __restrict__ deg,
    unsigned short* __restrict__ H, float* __restrict__ a_srcW,
    float* __restrict__ a_dstW) {
    __shared__ __align__(16) unsigned short As[64 * LDA3];
    __shared__ __align__(16) unsigned short Bs[272 * LDA3];
    const int t = threadIdx.x;
    const int wc = t >> 6, lane = t & 63;
    const int fr = lane & 15, fq = lane >> 4;
    const int m0 = blockIdx.x * 64;

    // degree histogram slice (overlaps staging/compute)
    {
        int probe = e[2 * lane + 1];
        unsigned long long nz = __ballot(probe != 0);
        bool is64 = (nz == 0ull);
        int tg = blockIdx.x * 256 + t;
        #pragma unroll
        for (int j = 0; j < 4; ++j) {
            int i = tg * 4 + j;
            if (i < NE) {
                int d = is64 ? e[2 * (NE + i)] : e[NE + i];
                atomicAdd(&deg[d], 1);
            }
        }
    }

    v4f acc[4][4];
    v4f acc4[4];
    #pragma unroll
    for (int mi = 0; mi < 4; ++mi) {
        acc4[mi] = (v4f){0.f, 0.f, 0.f, 0.f};
        #pragma unroll
        for (int j = 0; j < 4; ++j) acc[mi][j] = (v4f){0.f, 0.f, 0.f, 0.f};
    }

    #pragma unroll
    for (int kt = 0; kt < 256; kt += 64) {
        #pragma unroll
        for (int it = 0; it < 4; ++it) {
            int v = t + it * 256;
            int row = v >> 4;
            int c4 = (v & 15) << 2;
            int gr = m0 + row;
            float4 val = make_float4(0.f, 0.f, 0.f, 0.f);
            if (gr < NN) val = *(const float4*)(X + (size_t)gr * DIM + kt + c4);
            ushort4 o;
            o.x = f2b(val.x); o.y = f2b(val.y); o.z = f2b(val.z); o.w = f2b(val.w);
            *(ushort4*)(As + row * LDA3 + c4) = o;
        }
        #pragma unroll
        for (int it = 0; it < 9; ++it) {
            int v = t + it * 256;
            if (v < 2176) {
                int row = v >> 3;
                int kv = (v & 7) << 3;
                u16x8 val = *(const u16x8*)(Wt + (size_t)row * DIM + kt + kv);
                *(u16x8*)(Bs + row * LDA3 + kv) = val;
            }
        }
        __syncthreads();
        #pragma unroll
        for (int ks = 0; ks < 64; ks += 32) {
            v8s a[4];
            #pragma unroll
            for (int mi = 0; mi < 4; ++mi)
                a[mi] = *(const v8s*)(As + (mi * 16 + fr) * LDA3 + ks + fq * 8);
            #pragma unroll
            for (int j = 0; j < 4; ++j) {
                v8s b = *(const v8s*)(Bs + (wc * 64 + j * 16 + fr) * LDA3 + ks + fq * 8);
                #pragma unroll
                for (int mi = 0; mi < 4; ++mi)
                    acc[mi][j] = __builtin_amdgcn_mfma_f32_16x16x32_bf16(a[mi], b, acc[mi][j], 0, 0, 0);
            }
            if (wc == 0) {
                v8s b4 = *(const v8s*)(Bs + (256 + fr) * LDA3 + ks + fq * 8);
                #pragma unroll
                for (int mi = 0; mi < 4; ++mi)
                    acc4[mi] = __builtin_amdgcn_mfma_f32_16x16x32_bf16(a[mi], b4, acc4[mi], 0, 0, 0);
            }
        }
        __syncthreads();
    }
    #pragma unroll
    for (int mi = 0; mi < 4; ++mi)
        #pragma unroll
        for (int j = 0; j < 4; ++j)
            #pragma unroll
            for (int r = 0; r < 4; ++r) {
                int gr = m0 + mi * 16 + fq * 4 + r;
                int gc = wc * 64 + j * 16 + fr;
                if (gr < NN) H[(size_t)gr * DIM + gc] = f2b(acc[mi][j][r]);
            }
    if (wc == 0) {
        #pragma unroll
        for (int mi = 0; mi < 4; ++mi)
            #pragma unroll
            for (int r = 0; r < 4; ++r) {
                int gr = m0 + mi * 16 + fq * 4 + r;
                if (gr < NN) {
                    if (fr < 8) a_srcW[gr * NH + fr] = acc4[mi][r];
                    else        a_dstW[gr * NH + (fr - 8)] = acc4[mi][r];
                }
            }
    }
}

// --------------------------- single-pass decoupled-lookback exclusive scan
// 196 blocks, ticket-ordered; pay[b] = (value<<2)|flag, flag 1=agg, 2=incl.
// All 196 blocks are co-resident (196 < 256 CUs) so predecessor spin is safe.
__global__ __launch_bounds__(256) void scanlb_kernel(
    const int* __restrict__ deg, int* __restrict__ ticket, int* __restrict__ pay,
    int* __restrict__ row_start, int* __restrict__ cursor) {
    __shared__ int sbid;
    __shared__ int wt[4];
    __shared__ int sexcl;
    const int t = threadIdx.x;
    if (t == 0) sbid = atomicAdd(ticket, 1);
    __syncthreads();
    const int b = sbid;
    const int i = b * 256 + t;
    const int lane = t & 63, wave = t >> 6;
    int v = (i < NN) ? deg[i] : 0;
    int x = v;
    #pragma unroll
    for (int off = 1; off <= 32; off <<= 1) {
        int y = __shfl_up(x, off);
        if (lane >= off) x += y;
    }
    if (lane == 63) wt[wave] = x;
    __syncthreads();
    int add = 0;
    #pragma unroll
    for (int w2 = 0; w2 < 4; ++w2) if (w2 < wave) add += wt[w2];
    const int incl = x + add;
    const int total = wt[0] + wt[1] + wt[2] + wt[3];
    if (t == 0) {
        if (b > 0) atomicExch(&pay[b], (total << 2) | 1);
        int excl = 0;
        int p = b - 1;
        while (p >= 0) {
            int pv;
            do { pv = atomicAdd(&pay[p], 0); } while ((pv & 3) == 0);
            excl += (pv >> 2);
            if ((pv & 3) == 2) break;
            --p;
        }
        atomicExch(&pay[b], ((excl + total) << 2) | 2);
        sexcl = excl;
    }
    __syncthreads();
    const int excl = sexcl;
    if (i < NN) {
        int r = excl + incl - v;
        row_start[i] = r;
        cursor[i] = r;
    }
    if (b == NB - 1 && t == 255) row_start[NN] = excl + total;
}

// -------------------------------------- CSR fill + per-edge softmax weights
__global__ __launch_bounds__(256) void fill_kernel(
    const int* __restrict__ e, const float* __restrict__ a_src,
    const float* __restrict__ a_dst, int* __restrict__ cursor,
    int* __restrict__ csr_src, float* __restrict__ wcsr) {
    const int i = blockIdx.x * 256 + threadIdx.x;
    const int lane = threadIdx.x & 63;
    int probe = e[2 * lane + 1];
    unsigned long long nz = __ballot(probe != 0);
    bool is64 = (nz == 0ull);
    int s, d;
    if (is64) { s = e[2 * i]; d = e[2 * (NE + i)]; }
    else      { s = e[i];     d = e[NE + i]; }
    int pos = atomicAdd(&cursor[d], 1);
    csr_src[pos] = s;
    float4 as0 = *(const float4*)(a_src + s * NH);
    float4 as1 = *(const float4*)(a_src + s * NH + 4);
    float4 ad0 = *(const float4*)(a_dst + d * NH);
    float4 ad1 = *(const float4*)(a_dst + d * NH + 4);
    const float* asp0 = (const float*)&as0; const float* asp1 = (const float*)&as1;
    const float* adp0 = (const float*)&ad0; const float* adp1 = (const float*)&ad1;
    float4 w0, w1;
    float* wp0 = (float*)&w0; float* wp1 = (float*)&w1;
    #pragma unroll
    for (int h = 0; h < 4; ++h) {
        float lg = asp0[h] + adp0[h];
        lg = lg > 0.f ? lg : 0.2f * lg;
        wp0[h] = __expf(lg);
        float lg2 = asp1[h] + adp1[h];
        lg2 = lg2 > 0.f ? lg2 : 0.2f * lg2;
        wp1[h] = __expf(lg2);
    }
    *(float4*)(wcsr + pos * NH) = w0;
    *(float4*)(wcsr + pos * NH + 4) = w1;
}

// --------------------------------------- fused aggregate+ELU+LayerNorm
// one wave per dst node; 16-edge chunks, slot=lane>>5 takes 8 contiguous
// edges -> 8 independent csr/w loads then 8 independent H-row loads in
// flight. All hot-loop addressing is 32-bit.
__global__ __launch_bounds__(256) void agg_kernel(
    const unsigned short* __restrict__ H, const int* __restrict__ row_start,
    const int* __restrict__ csr_src, const float* __restrict__ wcsr,
    const float* __restrict__ X, const float* __restrict__ BIAS,
    const float* __restrict__ LNS, const float* __restrict__ LNB,
    float* __restrict__ OUT) {
    const int wave = threadIdx.x >> 6, lane = threadIdx.x & 63;
    const int d = blockIdx.x * 4 + wave;
    if (d >= NN) return;
    const int base = row_start[d];
    const int degree = row_start[d + 1] - base;
    const int slot = lane >> 5;
    const int q = lane & 31;
    const int headq = q >> 2;
    const int ch0 = q * 8;

    float4 x0 = *(const float4*)(X + d * DIM + ch0);
    float4 x1 = *(const float4*)(X + d * DIM + ch0 + 4);
    float4 b0 = *(const float4*)(BIAS + ch0);
    float4 b1 = *(const float4*)(BIAS + ch0 + 4);
    float4 sc0 = *(const float4*)(LNS + ch0);
    float4 sc1 = *(const float4*)(LNS + ch0 + 4);
    float4 lb0 = *(const float4*)(LNB + ch0);
    float4 lb1 = *(const float4*)(LNB + ch0 + 4);

    float acc[8];
    #pragma unroll
    for (int j = 0; j < 8; ++j) acc[j] = 0.f;
    float sumw = 0.f;

    for (int c0 = 0; c0 < degree; c0 += 16) {
        const int e0 = c0 + slot * 8;
        const int rem = degree - e0;
        const int eb = base + e0;
        int s[8]; float w[8];
        #pragma unroll
        for (int k = 0; k < 8; ++k) { s[k] = 0; w[k] = 0.f; }
        #pragma unroll
        for (int k = 0; k < 8; ++k)
            if (rem > k) {
                s[k] = csr_src[eb + k];
                w[k] = wcsr[(eb + k) * NH + headq];
            }
        u16x8 hv[8];
        #pragma unroll
        for (int k = 0; k < 8; ++k)
            hv[k] = *(const u16x8*)(H + s[k] * DIM + ch0);
        #pragma unroll
        for (int k = 0; k < 8; ++k) {
            sumw += w[k];
            #pragma unroll
            for (int j = 0; j < 8; ++j) acc[j] += w[k] * b2f(hv[k][j]);
        }
    }

    float sum_ex = sumw + __shfl_xor(sumw, 32);
    #pragma unroll
    for (int j = 0; j < 8; ++j) acc[j] += __shfl_xor(acc[j], 32);

    const float inv = 1.0f / (sum_ex + 1e-16f);

    const float* xp0 = (const float*)&x0; const float* xp1 = (const float*)&x1;
    const float* bp0 = (const float*)&b0; const float* bp1 = (const float*)&b1;
    float v[8];
    float s1v = 0.f, s2v = 0.f;
    #pragma unroll
    for (int j = 0; j < 8; ++j) {
        float xv = (j < 4) ? xp0[j] : xp1[j - 4];
        float bv = (j < 4) ? bp0[j] : bp1[j - 4];
        float t = acc[j] * inv + bv + xv;
        t = t > 0.f ? t : expm1f(t);   // ELU
        v[j] = t;
        s1v += t;
        s2v += t * t;
    }
    #pragma unroll
    for (int off = 16; off >= 1; off >>= 1) {
        s1v += __shfl_xor(s1v, off);
        s2v += __shfl_xor(s2v, off);
    }
    const float mean = s1v * (1.0f / 256.0f);
    float var = s2v * (1.0f / 256.0f) - mean * mean;
    var = fmaxf(var, 0.f);
    const float rstd = rsqrtf(var + 1e-5f);

    if (slot == 0) {
        const float* scp0 = (const float*)&sc0; const float* scp1 = (const float*)&sc1;
        const float* lbp0 = (const float*)&lb0; const float* lbp1 = (const float*)&lb1;
        float4 o0, o1;
        float* op0 = (float*)&o0; float* op1 = (float*)&o1;
        #pragma unroll
        for (int j = 0; j < 4; ++j) {
            op0[j] = (v[j] - mean) * rstd * scp0[j] + lbp0[j];
            op1[j] = (v[j + 4] - mean) * rstd * scp1[j] + lbp1[j];
        }
        *(float4*)(OUT + d * DIM + ch0) = o0;
        *(float4*)(OUT + d * DIM + ch0 + 4) = o1;
    }
}

// ---------------------------------------------------------------- launcher
extern "C" void kernel_launch(void* const* d_in, const int* in_sizes, int n_in,
                              void* d_out, int out_size, void* d_ws, size_t ws_size,
                              hipStream_t stream) {
    const float* X    = (const float*)d_in[0];
    const int*   EIDX = (const int*)d_in[1];
    const float* W    = (const float*)d_in[2];
    const float* ASRC = (const float*)d_in[3];
    const float* ADST = (const float*)d_in[4];
    const float* BIAS = (const float*)d_in[5];
    const float* LNS  = (const float*)d_in[6];
    const float* LNB  = (const float*)d_in[7];
    float* OUT = (float*)d_out;

    char* ws = (char*)d_ws;
    unsigned short* H   = (unsigned short*)(ws);                  // 25,600,000
    unsigned short* Wt  = (unsigned short*)(ws + 25600000);       //    139,264
    float* a_srcW       = (float*)(ws + 25739264);                //  1,600,000
    float* a_dstW       = (float*)(ws + 27339264);                //  1,600,000
    int*   deg          = (int*)(ws + 28939264);                  //    200,000
    int*   ticket       = (int*)(ws + 29139264);                  //          4
    int*   pay          = (int*)(ws + 29139268);                  //        784
    int*   row_start    = (int*)(ws + 29140064);                  //    200,016
    int*   cursor       = (int*)(ws + 29340080);                  //    200,000
    int*   csr_src      = (int*)(ws + 29540080);                  //  3,200,000
    float* wcsr         = (float*)(ws + 32740096);                // 25,600,000

    // deg + ticket + pay are contiguous: one memset covers all (200,788 B)
    hipMemsetAsync(deg, 0, 200788, stream);

    dim3 blk(256);
    prep_kernel<<<dim3(257), blk, 0, stream>>>(W, ASRC, ADST, Wt);
    gemm_kernel<<<dim3(782), blk, 0, stream>>>(X, Wt, EIDX, deg, H, a_srcW, a_dstW);
    scanlb_kernel<<<dim3(NB), blk, 0, stream>>>(deg, ticket, pay, row_start, cursor);
    fill_kernel<<<dim3(NE / 256), blk, 0, stream>>>(EIDX, a_srcW, a_dstW, cursor, csr_src, wcsr);
    agg_kernel<<<dim3((NN + 3) / 4), blk, 0, stream>>>(
        H, row_start, csr_src, wcsr, X, BIAS, LNS, LNB, OUT);
}